// Round 2
// baseline (1317.849 us; speedup 1.0000x reference)
//
#include <hip/hip_runtime.h>
#include <hip/hip_bf16.h>

#define B_   2
#define N_   2048
#define CIN  256
#define NH   8
#define CH   32

typedef unsigned short u16;
typedef __attribute__((ext_vector_type(4))) float f32x4;
typedef __bf16 bf16x8 __attribute__((ext_vector_type(8)));
typedef u16 u16x4 __attribute__((ext_vector_type(4)));
typedef u16 u16x8 __attribute__((ext_vector_type(8)));

static __device__ __forceinline__ u16 b16(float f) {
    __bf16 h = (__bf16)f;
    union { __bf16 h; u16 u; } c; c.h = h; return c.u;
}
static __device__ __forceinline__ float bf2f(u16 u) {
    union { unsigned u; float f; } c; c.u = ((unsigned)u) << 16; return c.f;
}
static __device__ __forceinline__ float sigmoidf_(float x) {
    return 1.0f / (1.0f + __expf(-x));
}
// async global->LDS DMA, 16B per lane; LDS dest = wave-uniform base + lane*16
static __device__ __forceinline__ void gload_lds16(const void* g, void* lds) {
    __builtin_amdgcn_global_load_lds(
        (const __attribute__((address_space(1))) unsigned int*)g,
        (__attribute__((address_space(3))) unsigned int*)lds, 16, 0, 0);
}

// ---------------------------------------------------------------------------
// DIAGNOSTIC ROUND: every kernel takes a runtime `reps` arg and redoes its
// (idempotent) work reps times, with a per-pass `asm ::: "memory"` fence so
// the compiler cannot hoist loads across passes. This pushes each kernel
// above the ~155us harness fill kernels so rocprof's top-5 finally shows
// per-kernel dur/hbm_gbps/FETCH/VALUBusy/MfmaUtil. Output values identical.
// ---------------------------------------------------------------------------

// ---------------------------------------------------------------------------
// K0: blocks [0,1024): convert qx,kvx -> bf16.
//     blocks [1024,1104): transpose+convert weights -> Wt[n][k] bf16
// ---------------------------------------------------------------------------
__global__ __launch_bounds__(256)
void prep_kernel(const float* __restrict__ qx, const float* __restrict__ kvx,
                 u16* __restrict__ qxb, u16* __restrict__ kvxb,
                 const float* __restrict__ Wq, const float* __restrict__ Wk,
                 const float* __restrict__ Wv, const float* __restrict__ Wg,
                 const float* __restrict__ Wo,
                 u16* __restrict__ WqT, u16* __restrict__ WkT,
                 u16* __restrict__ WvT, u16* __restrict__ WgT,
                 u16* __restrict__ WoT, int reps)
{
    const int flat = blockIdx.x;
    const int tid = threadIdx.x;
    __shared__ float T[64][65];

    for (int rep = 0; rep < reps; ++rep) {
        if (flat < 1024) {
            const int t = flat * 256 + tid;
            const int which = t >> 17;
            const size_t i = (size_t)(t & 131071) * 8;
            const float* s = which ? kvx : qx;
            u16* d = which ? kvxb : qxb;
            float4 a = *(const float4*)&s[i];
            float4 bv = *(const float4*)&s[i + 4];
            u16x8 o;
            o[0] = b16(a.x);  o[1] = b16(a.y);  o[2] = b16(a.z);  o[3] = b16(a.w);
            o[4] = b16(bv.x); o[5] = b16(bv.y); o[6] = b16(bv.z); o[7] = b16(bv.w);
            *(u16x8*)&d[i] = o;
        } else {
            const int wz = flat - 1024;
            const int z = wz >> 4, t16 = wz & 15;
            const int k0 = (t16 & 3) * 64, n0 = (t16 >> 2) * 64;
            const float* W = (z == 0) ? Wq : (z == 1) ? Wk : (z == 2) ? Wv : (z == 3) ? Wg : Wo;
            u16* Wt = (z == 0) ? WqT : (z == 1) ? WkT : (z == 2) ? WvT : (z == 3) ? WgT : WoT;
            const float s = (z == 0) ? 0.17677669529663687f : 1.0f;

            const int a = tid >> 4, c4 = (tid & 15) * 4;
#pragma unroll
            for (int i = 0; i < 4; i++) {
                float4 v = *(const float4*)&W[(size_t)(k0 + a + i * 16) * CIN + n0 + c4];
                T[a + i * 16][c4 + 0] = v.x * s; T[a + i * 16][c4 + 1] = v.y * s;
                T[a + i * 16][c4 + 2] = v.z * s; T[a + i * 16][c4 + 3] = v.w * s;
            }
            __syncthreads();
#pragma unroll
            for (int i = 0; i < 4; i++) {
                const int nr = a + i * 16;
                u16x4 o;
                o[0] = b16(T[c4 + 0][nr]); o[1] = b16(T[c4 + 1][nr]);
                o[2] = b16(T[c4 + 2][nr]); o[3] = b16(T[c4 + 3][nr]);
                *(u16x4*)&Wt[(size_t)(n0 + nr) * CIN + k0 + c4] = o;
            }
            __syncthreads();   // WAR guard: next rep rewrites T
        }
        asm volatile("" ::: "memory");
    }
}

// ---------------------------------------------------------------------------
// K1: MFMA projections (z=0 Q, z=1 K, z=3 G=sigmoid, z=2 Vt transposed)
// ---------------------------------------------------------------------------
__global__ __launch_bounds__(256)
void proj_mfma(const u16* __restrict__ qxb, const u16* __restrict__ kvxb,
               const u16* __restrict__ WqT, const u16* __restrict__ WkT,
               const u16* __restrict__ WvT, const u16* __restrict__ WgT,
               const float* __restrict__ bgv,
               u16* __restrict__ Qw, u16* __restrict__ Kw,
               u16* __restrict__ Vt, u16* __restrict__ Gw, int reps)
{
    const int z = blockIdx.z;
    const int tid = threadIdx.x, w = tid >> 6, l = tid & 63, lr = l & 15, lq = l >> 4;

    for (int rep = 0; rep < reps; ++rep) {
        f32x4 acc[4] = {{0,0,0,0},{0,0,0,0},{0,0,0,0},{0,0,0,0}};
        if (z != 2) {
            const u16* A = (z == 1) ? kvxb : qxb;
            const u16* W = (z == 0) ? WqT : (z == 1) ? WkT : WgT;
            const int m0 = blockIdx.y * 64 + w * 16;
            const int n0 = blockIdx.x * 64;
            const u16* Ap = A + (size_t)(m0 + lr) * CIN + lq * 8;
            const u16* Wp = W + (size_t)(n0 + lr) * CIN + lq * 8;
#pragma unroll
            for (int k0 = 0; k0 < CIN; k0 += 32) {
                bf16x8 af = *(const bf16x8*)(Ap + k0);
#pragma unroll
                for (int nt = 0; nt < 4; nt++) {
                    bf16x8 bf = *(const bf16x8*)(Wp + (size_t)nt * 16 * CIN + k0);
                    acc[nt] = __builtin_amdgcn_mfma_f32_16x16x32_bf16(af, bf, acc[nt], 0, 0, 0);
                }
            }
            if (z == 3) {
#pragma unroll
                for (int nt = 0; nt < 4; nt++) {
                    const int col = n0 + nt * 16 + lr;
                    const float bb = bgv[col];
#pragma unroll
                    for (int r = 0; r < 4; r++)
                        Gw[(size_t)(m0 + lq * 4 + r) * CIN + col] = b16(sigmoidf_(acc[nt][r] + bb));
                }
            } else {
                u16* D = (z == 0) ? Qw : Kw;
#pragma unroll
                for (int nt = 0; nt < 4; nt++)
#pragma unroll
                    for (int r = 0; r < 4; r++)
                        D[(size_t)(m0 + lq * 4 + r) * CIN + n0 + nt * 16 + lr] = b16(acc[nt][r]);
            }
        } else {
            const int c0 = blockIdx.x * 64 + w * 16;
            const int n0g = blockIdx.y * 64;
            const int bb_ = n0g >> 11, nl0 = n0g & (N_ - 1);
            const u16* Ap = WvT + (size_t)(c0 + lr) * CIN + lq * 8;
            const u16* Bp = kvxb + (size_t)(n0g + lr) * CIN + lq * 8;
#pragma unroll
            for (int k0 = 0; k0 < CIN; k0 += 32) {
                bf16x8 af = *(const bf16x8*)(Ap + k0);
#pragma unroll
                for (int nt = 0; nt < 4; nt++) {
                    bf16x8 bf = *(const bf16x8*)(Bp + (size_t)nt * 16 * CIN + k0);
                    acc[nt] = __builtin_amdgcn_mfma_f32_16x16x32_bf16(af, bf, acc[nt], 0, 0, 0);
                }
            }
#pragma unroll
            for (int nt = 0; nt < 4; nt++)
#pragma unroll
                for (int r = 0; r < 4; r++)
                    Vt[((size_t)bb_ * CIN + c0 + lq * 4 + r) * N_ + nl0 + nt * 16 + lr] = b16(acc[nt][r]);
        }
        asm volatile("" ::: "memory");
    }
}

// ---------------------------------------------------------------------------
// K2: flash attention, barrier-free (unchanged structure from round 1),
// wrapped in a reps loop with vmcnt(0) drain between passes. Pass-boundary
// DMA overlap is benign: wrapped tile indices rewrite identical bytes.
// ---------------------------------------------------------------------------
#define RMAX(x) { x = fmaxf(x, __shfl_xor(x, 1)); x = fmaxf(x, __shfl_xor(x, 2)); \
                  x = fmaxf(x, __shfl_xor(x, 4)); x = fmaxf(x, __shfl_xor(x, 8)); }
#define RSUM(x) { x += __shfl_xor(x, 1); x += __shfl_xor(x, 2); \
                  x += __shfl_xor(x, 4); x += __shfl_xor(x, 8); }

__global__ __launch_bounds__(256)
void attn_kernel(const u16* __restrict__ Qw, const u16* __restrict__ Kw,
                 const u16* __restrict__ Vt, const float* __restrict__ bias,
                 const u16* __restrict__ Gw, u16* __restrict__ Owg, int reps)
{
    const int bid = blockIdx.x;
    const int h = bid & 7, qt = (bid >> 3) & 31, b = bid >> 8;
    const int tid = threadIdx.x;
    const int w = tid >> 6, l = tid & 63, lr = l & 15, lq = l >> 4;
    const int qb = qt * 64;

    __shared__ __align__(16) float Bt[4][3][16][32];   // wave-private 3-buf bias
    __shared__ u16 Plds[4][8][4][16];                  // wave-private P staging

    const bf16x8 qf = *(const bf16x8*)(Qw + (size_t)(b * N_ + qb + w * 16 + lr) * CIN + h * CH + lq * 8);
    const u16* Kb = Kw + (size_t)(b * N_ + lr) * CIN + h * CH + lq * 8;
    const u16* Vb = Vt + (size_t)((b * NH + h) * CH + lr) * N_ + lq * 8;
    const float* biasW = bias + ((size_t)(b * NH + h) * N_ + qb + w * 16) * N_;

    const float* gl0 = biasW + (size_t)(l >> 3) * N_ + (l & 7) * 4;
    const float* gl1 = biasW + (size_t)(8 + (l >> 3)) * N_ + (l & 7) * 4;

#define STAGE(TT, BI) { \
    gload_lds16(gl0 + (size_t)(TT) * 32, &Bt[w][BI][0][0]); \
    gload_lds16(gl1 + (size_t)(TT) * 32, &Bt[w][BI][8][0]); }

#define KVLOAD(K) { kf0 = *(const bf16x8*)(Kb + (size_t)(K) * CIN); \
                    kf1 = *(const bf16x8*)(Kb + (size_t)((K) + 16) * CIN); \
                    vf0 = *(const bf16x8*)(Vb + (K)); \
                    vf1 = *(const bf16x8*)(Vb + 16 * N_ + (K)); }

    f32x4 acc0, acc1;
    float m0v, m1v, m2v, m3v, l0, l1, l2, l3;
    bf16x8 kf0, kf1, vf0, vf1;

    for (int rep = 0; rep < reps; ++rep) {
        asm volatile("s_waitcnt vmcnt(0)" ::: "memory");   // clean pass boundary
        acc0 = (f32x4){0.f, 0.f, 0.f, 0.f}; acc1 = (f32x4){0.f, 0.f, 0.f, 0.f};
        m0v = 8.f; m1v = 8.f; m2v = 8.f; m3v = 8.f;        // defer-max init
        l0 = 0.f; l1 = 0.f; l2 = 0.f; l3 = 0.f;

        STAGE(0, 0)
        __builtin_amdgcn_sched_barrier(0);
        KVLOAD(0)
        __builtin_amdgcn_sched_barrier(0);
        STAGE(1, 1)
        __builtin_amdgcn_sched_barrier(0);

        int cur = 0, nxt = 2;
        for (int t = 0; t < 64; t++) {
            // outstanding: [S(t-2):2][K(t-1):4][S(t-1):2] -> keep newest 2
            asm volatile("s_waitcnt vmcnt(2)" ::: "memory");
            const bf16x8 ck0 = kf0, ck1 = kf1, cv0 = vf0, cv1 = vf1;
            KVLOAD(((t + 1) & 63) * 32)
            __builtin_amdgcn_sched_barrier(0);
            STAGE((t + 2) & 63, nxt)
            __builtin_amdgcn_sched_barrier(0);

            const float* bt = &Bt[w][cur][lq * 4][0];
            f32x4 c0, c1;
            c0[0] = bt[0 * 32 + lr];      c0[1] = bt[1 * 32 + lr];
            c0[2] = bt[2 * 32 + lr];      c0[3] = bt[3 * 32 + lr];
            c1[0] = bt[0 * 32 + 16 + lr]; c1[1] = bt[1 * 32 + 16 + lr];
            c1[2] = bt[2 * 32 + 16 + lr]; c1[3] = bt[3 * 32 + 16 + lr];

            f32x4 s0 = __builtin_amdgcn_mfma_f32_16x16x32_bf16(qf, ck0, c0, 0, 0, 0);
            f32x4 s1 = __builtin_amdgcn_mfma_f32_16x16x32_bf16(qf, ck1, c1, 0, 0, 0);

            float pm0 = fmaxf(s0[0], s1[0]);
            float pm1 = fmaxf(s0[1], s1[1]);
            float pm2 = fmaxf(s0[2], s1[2]);
            float pm3 = fmaxf(s0[3], s1[3]);
            bool ev = (pm0 > m0v) || (pm1 > m1v) || (pm2 > m2v) || (pm3 > m3v);
            if (__any(ev)) {
                RMAX(pm0) RMAX(pm1) RMAX(pm2) RMAX(pm3)
                float t0 = fmaxf(m0v, pm0), t1 = fmaxf(m1v, pm1);
                float t2 = fmaxf(m2v, pm2), t3 = fmaxf(m3v, pm3);
                float sc0 = __expf(m0v - t0), sc1 = __expf(m1v - t1);
                float sc2 = __expf(m2v - t2), sc3 = __expf(m3v - t3);
                m0v = t0; m1v = t1; m2v = t2; m3v = t3;
                l0 *= sc0; l1 *= sc1; l2 *= sc2; l3 *= sc3;
                acc0[0] *= sc0; acc0[1] *= sc1; acc0[2] *= sc2; acc0[3] *= sc3;
                acc1[0] *= sc0; acc1[1] *= sc1; acc1[2] *= sc2; acc1[3] *= sc3;
            }
            float p00 = __expf(s0[0] - m0v), p01 = __expf(s0[1] - m1v);
            float p02 = __expf(s0[2] - m2v), p03 = __expf(s0[3] - m3v);
            float p10 = __expf(s1[0] - m0v), p11 = __expf(s1[1] - m1v);
            float p12 = __expf(s1[2] - m2v), p13 = __expf(s1[3] - m3v);
            l0 += p00 + p10; l1 += p01 + p11; l2 += p02 + p12; l3 += p03 + p13;

            u16* pw = &Plds[w][0][lq][lr];
            pw[0 * 64] = b16(p00); pw[1 * 64] = b16(p01);
            pw[2 * 64] = b16(p02); pw[3 * 64] = b16(p03);
            pw[4 * 64] = b16(p10); pw[5 * 64] = b16(p11);
            pw[6 * 64] = b16(p12); pw[7 * 64] = b16(p13);

            const bf16x8 pa = *(const bf16x8*)&Plds[w][(lq >> 1) * 4 + (lr & 3)][lr >> 2][(lq & 1) * 8];
            acc0 = __builtin_amdgcn_mfma_f32_16x16x32_bf16(pa, cv0, acc0, 0, 0, 0);
            acc1 = __builtin_amdgcn_mfma_f32_16x16x32_bf16(pa, cv1, acc1, 0, 0, 0);

            cur = (cur == 2) ? 0 : cur + 1;
            nxt = (nxt == 2) ? 0 : nxt + 1;
        }
        asm volatile("" ::: "memory");
    }
#undef STAGE
#undef KVLOAD

    RSUM(l0) RSUM(l1) RSUM(l2) RSUM(l3)
    const float rr[4] = {1.0f / l0, 1.0f / l1, 1.0f / l2, 1.0f / l3};
    const f32x4 a0 = acc0, a1 = acc1;

    const u16* Gb = Gw + (size_t)(b * N_ + qb + w * 16 + lq * 4) * CIN + h * CH + lr;
    u16* Ob = Owg + (size_t)(b * N_ + qb + w * 16 + lq * 4) * CIN + h * CH + lr;
#pragma unroll
    for (int r = 0; r < 4; r++) {
        const float g0 = bf2f(Gb[r * CIN]), g1 = bf2f(Gb[r * CIN + 16]);
        Ob[r * CIN]      = b16(a0[r] * rr[r] * g0);
        Ob[r * CIN + 16] = b16(a1[r] * rr[r] * g1);
    }
}

// ---------------------------------------------------------------------------
// K3: out = Owg @ Wo + bo  (MFMA, f32 output)
// ---------------------------------------------------------------------------
__global__ __launch_bounds__(256)
void out_mfma(const u16* __restrict__ Owg, const u16* __restrict__ WoT,
              const float* __restrict__ bo, float* __restrict__ out, int reps)
{
    const int tid = threadIdx.x, w = tid >> 6, l = tid & 63, lr = l & 15, lq = l >> 4;
    const int m0 = blockIdx.y * 64 + w * 16, n0 = blockIdx.x * 64;
    const u16* Ap = Owg + (size_t)(m0 + lr) * CIN + lq * 8;
    const u16* Wp = WoT + (size_t)(n0 + lr) * CIN + lq * 8;
    for (int rep = 0; rep < reps; ++rep) {
        f32x4 acc[4] = {{0,0,0,0},{0,0,0,0},{0,0,0,0},{0,0,0,0}};
#pragma unroll
        for (int k0 = 0; k0 < CIN; k0 += 32) {
            bf16x8 af = *(const bf16x8*)(Ap + k0);
#pragma unroll
            for (int nt = 0; nt < 4; nt++) {
                bf16x8 bf = *(const bf16x8*)(Wp + (size_t)nt * 16 * CIN + k0);
                acc[nt] = __builtin_amdgcn_mfma_f32_16x16x32_bf16(af, bf, acc[nt], 0, 0, 0);
            }
        }
#pragma unroll
        for (int nt = 0; nt < 4; nt++) {
            const float bb = bo[n0 + nt * 16 + lr];
#pragma unroll
            for (int r = 0; r < 4; r++)
                out[(size_t)(m0 + lq * 4 + r) * CIN + n0 + nt * 16 + lr] = acc[nt][r] + bb;
        }
        asm volatile("" ::: "memory");
    }
}

// ---------------------------------------------------------------------------
extern "C" void kernel_launch(void* const* d_in, const int* in_sizes, int n_in,
                              void* d_out, int out_size, void* d_ws, size_t ws_size,
                              hipStream_t stream)
{
    const float* qx   = (const float*)d_in[0];
    const float* kvx  = (const float*)d_in[1];
    const float* bias = (const float*)d_in[2];
    const float* Wq = (const float*)d_in[3];
    const float* Wk = (const float*)d_in[4];
    const float* Wv = (const float*)d_in[5];
    const float* Wg = (const float*)d_in[6];
    const float* bg = (const float*)d_in[7];
    const float* Wo = (const float*)d_in[8];
    const float* bo = (const float*)d_in[9];
    float* out = (float*)d_out;

    char* ws = (char*)d_ws;
    const size_t SZB = (size_t)B_ * N_ * CIN * 2;   // 2 MB per bf16 [4096][256]
    u16* qxb  = (u16*)(ws + 0 * SZB);
    u16* kvxb = (u16*)(ws + 1 * SZB);
    u16* Qw   = (u16*)(ws + 2 * SZB);
    u16* Kw   = (u16*)(ws + 3 * SZB);
    u16* Vt   = (u16*)(ws + 4 * SZB);
    u16* Gw   = (u16*)(ws + 5 * SZB);
    u16* Owg  = (u16*)(ws + 6 * SZB);
    const size_t WSZ = (size_t)CIN * CIN * 2;       // 128 KB per bf16 weight
    u16* WqT = (u16*)(ws + 7 * SZB + 0 * WSZ);
    u16* WkT = (u16*)(ws + 7 * SZB + 1 * WSZ);
    u16* WvT = (u16*)(ws + 7 * SZB + 2 * WSZ);
    u16* WgT = (u16*)(ws + 7 * SZB + 3 * WSZ);
    u16* WoT = (u16*)(ws + 7 * SZB + 4 * WSZ);

    // Diagnostic multipliers: push every kernel above the ~155us fill kernels
    // so rocprof top-5 shows all four with counters. Per-kernel true time =
    // dispatch dur / reps.
    prep_kernel<<<dim3(1104), 256, 0, stream>>>(qx, kvx, qxb, kvxb,
                                                Wq, Wk, Wv, Wg, Wo,
                                                WqT, WkT, WvT, WgT, WoT, 96);
    proj_mfma<<<dim3(4, 64, 4), 256, 0, stream>>>(qxb, kvxb, WqT, WkT, WvT, WgT,
                                                  bg, Qw, Kw, Vt, Gw, 48);
    attn_kernel<<<dim3(512), 256, 0, stream>>>(Qw, Kw, Vt, bias, Gw, Owg, 4);
    out_mfma<<<dim3(4, 64, 1), 256, 0, stream>>>(Owg, WoT, bo, out, 96);
}

// Round 3
// 111.055 us; speedup vs baseline: 11.8666x; 11.8666x over previous
//
#include <hip/hip_runtime.h>
#include <hip/hip_bf16.h>

#define B_   2
#define N_   2048
#define CIN  256
#define NH   8
#define CH   32

typedef unsigned short u16;
typedef __attribute__((ext_vector_type(4))) float f32x4;
typedef __bf16 bf16x8 __attribute__((ext_vector_type(8)));
typedef u16 u16x4 __attribute__((ext_vector_type(4)));
typedef u16 u16x8 __attribute__((ext_vector_type(8)));

static __device__ __forceinline__ u16 b16(float f) {
    __bf16 h = (__bf16)f;
    union { __bf16 h; u16 u; } c; c.h = h; return c.u;
}
static __device__ __forceinline__ float bf2f(u16 u) {
    union { unsigned u; float f; } c; c.u = ((unsigned)u) << 16; return c.f;
}
static __device__ __forceinline__ float sigmoidf_(float x) {
    return 1.0f / (1.0f + __expf(-x));
}
// async global->LDS DMA, 16B per lane; LDS dest = wave-uniform base + lane*16
static __device__ __forceinline__ void gload_lds16(const void* g, void* lds) {
    __builtin_amdgcn_global_load_lds(
        (const __attribute__((address_space(1))) unsigned int*)g,
        (__attribute__((address_space(3))) unsigned int*)lds, 16, 0, 0);
}

// ---------------------------------------------------------------------------
// K0: blocks [0,1024): convert qx,kvx -> bf16.
//     blocks [1024,1104): transpose+convert weights -> Wt[n][k] bf16
// ---------------------------------------------------------------------------
__global__ __launch_bounds__(256)
void prep_kernel(const float* __restrict__ qx, const float* __restrict__ kvx,
                 u16* __restrict__ qxb, u16* __restrict__ kvxb,
                 const float* __restrict__ Wq, const float* __restrict__ Wk,
                 const float* __restrict__ Wv, const float* __restrict__ Wg,
                 const float* __restrict__ Wo,
                 u16* __restrict__ WqT, u16* __restrict__ WkT,
                 u16* __restrict__ WvT, u16* __restrict__ WgT,
                 u16* __restrict__ WoT)
{
    const int flat = blockIdx.x;
    const int tid = threadIdx.x;
    if (flat < 1024) {
        const int t = flat * 256 + tid;
        const int which = t >> 17;
        const size_t i = (size_t)(t & 131071) * 8;
        const float* s = which ? kvx : qx;
        u16* d = which ? kvxb : qxb;
        float4 a = *(const float4*)&s[i];
        float4 bv = *(const float4*)&s[i + 4];
        u16x8 o;
        o[0] = b16(a.x);  o[1] = b16(a.y);  o[2] = b16(a.z);  o[3] = b16(a.w);
        o[4] = b16(bv.x); o[5] = b16(bv.y); o[6] = b16(bv.z); o[7] = b16(bv.w);
        *(u16x8*)&d[i] = o;
        return;
    }
    const int wz = flat - 1024;
    const int z = wz >> 4, t16 = wz & 15;
    const int k0 = (t16 & 3) * 64, n0 = (t16 >> 2) * 64;
    const float* W = (z == 0) ? Wq : (z == 1) ? Wk : (z == 2) ? Wv : (z == 3) ? Wg : Wo;
    u16* Wt = (z == 0) ? WqT : (z == 1) ? WkT : (z == 2) ? WvT : (z == 3) ? WgT : WoT;
    const float s = (z == 0) ? 0.17677669529663687f : 1.0f;

    __shared__ float T[64][65];
    const int a = tid >> 4, c4 = (tid & 15) * 4;
#pragma unroll
    for (int i = 0; i < 4; i++) {
        float4 v = *(const float4*)&W[(size_t)(k0 + a + i * 16) * CIN + n0 + c4];
        T[a + i * 16][c4 + 0] = v.x * s; T[a + i * 16][c4 + 1] = v.y * s;
        T[a + i * 16][c4 + 2] = v.z * s; T[a + i * 16][c4 + 3] = v.w * s;
    }
    __syncthreads();
#pragma unroll
    for (int i = 0; i < 4; i++) {
        const int nr = a + i * 16;
        u16x4 o;
        o[0] = b16(T[c4 + 0][nr]); o[1] = b16(T[c4 + 1][nr]);
        o[2] = b16(T[c4 + 2][nr]); o[3] = b16(T[c4 + 3][nr]);
        *(u16x4*)&Wt[(size_t)(n0 + nr) * CIN + k0 + c4] = o;
    }
}

// ---------------------------------------------------------------------------
// Staged 64x64 GEMM-tile core (used by proj & out).
// A-tile/B-tile = 64 rows x 256 k (bf16) staged into padded LDS [64][136]
// (row stride 272B; 272 mod 128 = 16B -> fragment ds_read_b128 at the LDS
// bandwidth floor, no conflict surcharge). Two K=128 phases; phase-1 global
// loads issued BEFORE phase-0 compute (async-split) so latency hides under
// MFMA. K-loop touches only LDS. Accumulation order identical to the
// unstaged version -> bit-identical results.
// ---------------------------------------------------------------------------
#define LDW 136   // padded row length in u16

static __device__ __forceinline__ void stage_phase0(
    const u16* __restrict__ src, u16 (*dst)[LDW], int tid)
{
#pragma unroll
    for (int i = 0; i < 4; i++) {
        const int e = tid + 256 * i;          // 1024 chunks of 16B
        const int row = e >> 4, c = e & 15;
        bf16x8 v = *(const bf16x8*)(src + (size_t)row * CIN + c * 8);
        *(bf16x8*)&dst[row][c * 8] = v;
    }
}
static __device__ __forceinline__ void load_phase1(
    const u16* __restrict__ src, bf16x8 r[4], int tid)
{
#pragma unroll
    for (int i = 0; i < 4; i++) {
        const int e = tid + 256 * i;
        const int row = e >> 4, c = e & 15;
        r[i] = *(const bf16x8*)(src + (size_t)row * CIN + 128 + c * 8);
    }
}
static __device__ __forceinline__ void write_phase1(
    const bf16x8 r[4], u16 (*dst)[LDW], int tid)
{
#pragma unroll
    for (int i = 0; i < 4; i++) {
        const int e = tid + 256 * i;
        const int row = e >> 4, c = e & 15;
        *(bf16x8*)&dst[row][c * 8] = r[i];
    }
}
static __device__ __forceinline__ void compute_phase(
    const u16 (*At)[LDW], const u16 (*Bt)[LDW],
    int w, int lr, int lq, f32x4 acc[4])
{
#pragma unroll
    for (int kk = 0; kk < 128; kk += 32) {
        bf16x8 af = *(const bf16x8*)&At[w * 16 + lr][kk + lq * 8];
#pragma unroll
        for (int nt = 0; nt < 4; nt++) {
            bf16x8 bf = *(const bf16x8*)&Bt[nt * 16 + lr][kk + lq * 8];
            acc[nt] = __builtin_amdgcn_mfma_f32_16x16x32_bf16(af, bf, acc[nt], 0, 0, 0);
        }
    }
}

// ---------------------------------------------------------------------------
// K1: MFMA projections (z=0 Q, z=1 K, z=3 G=sigmoid, z=2 Vt transposed)
// ---------------------------------------------------------------------------
__global__ __launch_bounds__(256, 4)
void proj_mfma(const u16* __restrict__ qxb, const u16* __restrict__ kvxb,
               const u16* __restrict__ WqT, const u16* __restrict__ WkT,
               const u16* __restrict__ WvT, const u16* __restrict__ WgT,
               const float* __restrict__ bgv,
               u16* __restrict__ Qw, u16* __restrict__ Kw,
               u16* __restrict__ Vt, u16* __restrict__ Gw)
{
    const int z = blockIdx.z;
    const int tid = threadIdx.x, w = tid >> 6, l = tid & 63, lr = l & 15, lq = l >> 4;

    __shared__ u16 At[64][LDW];
    __shared__ u16 Bt[64][LDW];

    const u16* Arows;
    const u16* Brows;
    if (z != 2) {
        Arows = ((z == 1) ? kvxb : qxb) + (size_t)(blockIdx.y * 64) * CIN;
        Brows = ((z == 0) ? WqT : (z == 1) ? WkT : WgT) + (size_t)(blockIdx.x * 64) * CIN;
    } else {
        Arows = WvT + (size_t)(blockIdx.x * 64) * CIN;
        Brows = kvxb + (size_t)(blockIdx.y * 64) * CIN;
    }

    f32x4 acc[4] = {{0,0,0,0},{0,0,0,0},{0,0,0,0},{0,0,0,0}};

    stage_phase0(Arows, At, tid);
    stage_phase0(Brows, Bt, tid);
    __syncthreads();
    bf16x8 ra[4], rb[4];
    load_phase1(Arows, ra, tid);          // issue now, consume after compute
    load_phase1(Brows, rb, tid);
    compute_phase(At, Bt, w, lr, lq, acc);
    __syncthreads();                       // WAR: all reads of phase-0 done
    write_phase1(ra, At, tid);
    write_phase1(rb, Bt, tid);
    __syncthreads();
    compute_phase(At, Bt, w, lr, lq, acc);

    if (z != 2) {
        const int m0 = blockIdx.y * 64 + w * 16;
        const int n0 = blockIdx.x * 64;
        if (z == 3) {
#pragma unroll
            for (int nt = 0; nt < 4; nt++) {
                const int col = n0 + nt * 16 + lr;
                const float bb = bgv[col];
#pragma unroll
                for (int r = 0; r < 4; r++)
                    Gw[(size_t)(m0 + lq * 4 + r) * CIN + col] = b16(sigmoidf_(acc[nt][r] + bb));
            }
        } else {
            u16* D = (z == 0) ? Qw : Kw;
#pragma unroll
            for (int nt = 0; nt < 4; nt++)
#pragma unroll
                for (int r = 0; r < 4; r++)
                    D[(size_t)(m0 + lq * 4 + r) * CIN + n0 + nt * 16 + lr] = b16(acc[nt][r]);
        }
    } else {
        const int c0 = blockIdx.x * 64 + w * 16;
        const int n0g = blockIdx.y * 64;
        const int bb_ = n0g >> 11, nl0 = n0g & (N_ - 1);
#pragma unroll
        for (int nt = 0; nt < 4; nt++)
#pragma unroll
            for (int r = 0; r < 4; r++)
                Vt[((size_t)bb_ * CIN + c0 + lq * 4 + r) * N_ + nl0 + nt * 16 + lr] = b16(acc[nt][r]);
    }
}

// ---------------------------------------------------------------------------
// K2: flash attention, barrier-free (round-1 structure, unchanged).
// ---------------------------------------------------------------------------
#define RMAX(x) { x = fmaxf(x, __shfl_xor(x, 1)); x = fmaxf(x, __shfl_xor(x, 2)); \
                  x = fmaxf(x, __shfl_xor(x, 4)); x = fmaxf(x, __shfl_xor(x, 8)); }
#define RSUM(x) { x += __shfl_xor(x, 1); x += __shfl_xor(x, 2); \
                  x += __shfl_xor(x, 4); x += __shfl_xor(x, 8); }

__global__ __launch_bounds__(256)
void attn_kernel(const u16* __restrict__ Qw, const u16* __restrict__ Kw,
                 const u16* __restrict__ Vt, const float* __restrict__ bias,
                 const u16* __restrict__ Gw, u16* __restrict__ Owg)
{
    const int bid = blockIdx.x;
    const int h = bid & 7, qt = (bid >> 3) & 31, b = bid >> 8;
    const int tid = threadIdx.x;
    const int w = tid >> 6, l = tid & 63, lr = l & 15, lq = l >> 4;
    const int qb = qt * 64;

    __shared__ __align__(16) float Btl[4][3][16][32];  // wave-private 3-buf bias
    __shared__ u16 Plds[4][8][4][16];                  // wave-private P staging

    const bf16x8 qf = *(const bf16x8*)(Qw + (size_t)(b * N_ + qb + w * 16 + lr) * CIN + h * CH + lq * 8);
    const u16* Kb = Kw + (size_t)(b * N_ + lr) * CIN + h * CH + lq * 8;
    const u16* Vb = Vt + (size_t)((b * NH + h) * CH + lr) * N_ + lq * 8;
    const float* biasW = bias + ((size_t)(b * NH + h) * N_ + qb + w * 16) * N_;

    const float* gl0 = biasW + (size_t)(l >> 3) * N_ + (l & 7) * 4;
    const float* gl1 = biasW + (size_t)(8 + (l >> 3)) * N_ + (l & 7) * 4;

#define STAGE(TT, BI) { \
    gload_lds16(gl0 + (size_t)(TT) * 32, &Btl[w][BI][0][0]); \
    gload_lds16(gl1 + (size_t)(TT) * 32, &Btl[w][BI][8][0]); }

#define KVLOAD(K) { kf0 = *(const bf16x8*)(Kb + (size_t)(K) * CIN); \
                    kf1 = *(const bf16x8*)(Kb + (size_t)((K) + 16) * CIN); \
                    vf0 = *(const bf16x8*)(Vb + (K)); \
                    vf1 = *(const bf16x8*)(Vb + 16 * N_ + (K)); }

    f32x4 acc0 = {0.f, 0.f, 0.f, 0.f}, acc1 = {0.f, 0.f, 0.f, 0.f};
    float m0v = 8.f, m1v = 8.f, m2v = 8.f, m3v = 8.f;   // defer-max init
    float l0 = 0.f, l1 = 0.f, l2 = 0.f, l3 = 0.f;
    bf16x8 kf0, kf1, vf0, vf1;

    STAGE(0, 0)
    __builtin_amdgcn_sched_barrier(0);
    KVLOAD(0)
    __builtin_amdgcn_sched_barrier(0);
    STAGE(1, 1)
    __builtin_amdgcn_sched_barrier(0);

    int cur = 0, nxt = 2;
    for (int t = 0; t < 64; t++) {
        // outstanding: [S(t-2):2][K(t-1):4][S(t-1):2] -> keep newest 2
        asm volatile("s_waitcnt vmcnt(2)" ::: "memory");
        const bf16x8 ck0 = kf0, ck1 = kf1, cv0 = vf0, cv1 = vf1;
        KVLOAD(((t + 1) & 63) * 32)
        __builtin_amdgcn_sched_barrier(0);
        STAGE((t + 2) & 63, nxt)
        __builtin_amdgcn_sched_barrier(0);

        const float* bt = &Btl[w][cur][lq * 4][0];
        f32x4 c0, c1;
        c0[0] = bt[0 * 32 + lr];      c0[1] = bt[1 * 32 + lr];
        c0[2] = bt[2 * 32 + lr];      c0[3] = bt[3 * 32 + lr];
        c1[0] = bt[0 * 32 + 16 + lr]; c1[1] = bt[1 * 32 + 16 + lr];
        c1[2] = bt[2 * 32 + 16 + lr]; c1[3] = bt[3 * 32 + 16 + lr];

        f32x4 s0 = __builtin_amdgcn_mfma_f32_16x16x32_bf16(qf, ck0, c0, 0, 0, 0);
        f32x4 s1 = __builtin_amdgcn_mfma_f32_16x16x32_bf16(qf, ck1, c1, 0, 0, 0);

        float pm0 = fmaxf(s0[0], s1[0]);
        float pm1 = fmaxf(s0[1], s1[1]);
        float pm2 = fmaxf(s0[2], s1[2]);
        float pm3 = fmaxf(s0[3], s1[3]);
        bool ev = (pm0 > m0v) || (pm1 > m1v) || (pm2 > m2v) || (pm3 > m3v);
        if (__any(ev)) {
            RMAX(pm0) RMAX(pm1) RMAX(pm2) RMAX(pm3)
            float t0 = fmaxf(m0v, pm0), t1 = fmaxf(m1v, pm1);
            float t2 = fmaxf(m2v, pm2), t3 = fmaxf(m3v, pm3);
            float sc0 = __expf(m0v - t0), sc1 = __expf(m1v - t1);
            float sc2 = __expf(m2v - t2), sc3 = __expf(m3v - t3);
            m0v = t0; m1v = t1; m2v = t2; m3v = t3;
            l0 *= sc0; l1 *= sc1; l2 *= sc2; l3 *= sc3;
            acc0[0] *= sc0; acc0[1] *= sc1; acc0[2] *= sc2; acc0[3] *= sc3;
            acc1[0] *= sc0; acc1[1] *= sc1; acc1[2] *= sc2; acc1[3] *= sc3;
        }
        float p00 = __expf(s0[0] - m0v), p01 = __expf(s0[1] - m1v);
        float p02 = __expf(s0[2] - m2v), p03 = __expf(s0[3] - m3v);
        float p10 = __expf(s1[0] - m0v), p11 = __expf(s1[1] - m1v);
        float p12 = __expf(s1[2] - m2v), p13 = __expf(s1[3] - m3v);
        l0 += p00 + p10; l1 += p01 + p11; l2 += p02 + p12; l3 += p03 + p13;

        u16* pw = &Plds[w][0][lq][lr];
        pw[0 * 64] = b16(p00); pw[1 * 64] = b16(p01);
        pw[2 * 64] = b16(p02); pw[3 * 64] = b16(p03);
        pw[4 * 64] = b16(p10); pw[5 * 64] = b16(p11);
        pw[6 * 64] = b16(p12); pw[7 * 64] = b16(p13);

        const bf16x8 pa = *(const bf16x8*)&Plds[w][(lq >> 1) * 4 + (lr & 3)][lr >> 2][(lq & 1) * 8];
        acc0 = __builtin_amdgcn_mfma_f32_16x16x32_bf16(pa, cv0, acc0, 0, 0, 0);
        acc1 = __builtin_amdgcn_mfma_f32_16x16x32_bf16(pa, cv1, acc1, 0, 0, 0);

        cur = (cur == 2) ? 0 : cur + 1;
        nxt = (nxt == 2) ? 0 : nxt + 1;
    }
#undef STAGE
#undef KVLOAD

    RSUM(l0) RSUM(l1) RSUM(l2) RSUM(l3)
    const float rr[4] = {1.0f / l0, 1.0f / l1, 1.0f / l2, 1.0f / l3};
    const f32x4 a0 = acc0, a1 = acc1;

    const u16* Gb = Gw + (size_t)(b * N_ + qb + w * 16 + lq * 4) * CIN + h * CH + lr;
    u16* Ob = Owg + (size_t)(b * N_ + qb + w * 16 + lq * 4) * CIN + h * CH + lr;
#pragma unroll
    for (int r = 0; r < 4; r++) {
        const float g0 = bf2f(Gb[r * CIN]), g1 = bf2f(Gb[r * CIN + 16]);
        Ob[r * CIN]      = b16(a0[r] * rr[r] * g0);
        Ob[r * CIN + 16] = b16(a1[r] * rr[r] * g1);
    }
}

// ---------------------------------------------------------------------------
// K3: out = Owg @ Wo + bo  (MFMA, f32 output) — same staged-tile core
// ---------------------------------------------------------------------------
__global__ __launch_bounds__(256, 4)
void out_mfma(const u16* __restrict__ Owg, const u16* __restrict__ WoT,
              const float* __restrict__ bo, float* __restrict__ out)
{
    const int tid = threadIdx.x, w = tid >> 6, l = tid & 63, lr = l & 15, lq = l >> 4;
    const int m0 = blockIdx.y * 64 + w * 16, n0 = blockIdx.x * 64;

    __shared__ u16 At[64][LDW];
    __shared__ u16 Bt[64][LDW];

    const u16* Arows = Owg + (size_t)(blockIdx.y * 64) * CIN;
    const u16* Brows = WoT + (size_t)(blockIdx.x * 64) * CIN;

    f32x4 acc[4] = {{0,0,0,0},{0,0,0,0},{0,0,0,0},{0,0,0,0}};

    stage_phase0(Arows, At, tid);
    stage_phase0(Brows, Bt, tid);
    __syncthreads();
    bf16x8 ra[4], rb[4];
    load_phase1(Arows, ra, tid);
    load_phase1(Brows, rb, tid);
    compute_phase(At, Bt, w, lr, lq, acc);
    __syncthreads();
    write_phase1(ra, At, tid);
    write_phase1(rb, Bt, tid);
    __syncthreads();
    compute_phase(At, Bt, w, lr, lq, acc);

#pragma unroll
    for (int nt = 0; nt < 4; nt++) {
        const float bb = bo[n0 + nt * 16 + lr];
#pragma unroll
        for (int r = 0; r < 4; r++)
            out[(size_t)(m0 + lq * 4 + r) * CIN + n0 + nt * 16 + lr] = acc[nt][r] + bb;
    }
}

// ---------------------------------------------------------------------------
extern "C" void kernel_launch(void* const* d_in, const int* in_sizes, int n_in,
                              void* d_out, int out_size, void* d_ws, size_t ws_size,
                              hipStream_t stream)
{
    const float* qx   = (const float*)d_in[0];
    const float* kvx  = (const float*)d_in[1];
    const float* bias = (const float*)d_in[2];
    const float* Wq = (const float*)d_in[3];
    const float* Wk = (const float*)d_in[4];
    const float* Wv = (const float*)d_in[5];
    const float* Wg = (const float*)d_in[6];
    const float* bg = (const float*)d_in[7];
    const float* Wo = (const float*)d_in[8];
    const float* bo = (const float*)d_in[9];
    float* out = (float*)d_out;

    char* ws = (char*)d_ws;
    const size_t SZB = (size_t)B_ * N_ * CIN * 2;   // 2 MB per bf16 [4096][256]
    u16* qxb  = (u16*)(ws + 0 * SZB);
    u16* kvxb = (u16*)(ws + 1 * SZB);
    u16* Qw   = (u16*)(ws + 2 * SZB);
    u16* Kw   = (u16*)(ws + 3 * SZB);
    u16* Vt   = (u16*)(ws + 4 * SZB);
    u16* Gw   = (u16*)(ws + 5 * SZB);
    u16* Owg  = (u16*)(ws + 6 * SZB);
    const size_t WSZ = (size_t)CIN * CIN * 2;       // 128 KB per bf16 weight
    u16* WqT = (u16*)(ws + 7 * SZB + 0 * WSZ);
    u16* WkT = (u16*)(ws + 7 * SZB + 1 * WSZ);
    u16* WvT = (u16*)(ws + 7 * SZB + 2 * WSZ);
    u16* WgT = (u16*)(ws + 7 * SZB + 3 * WSZ);
    u16* WoT = (u16*)(ws + 7 * SZB + 4 * WSZ);

    prep_kernel<<<dim3(1104), 256, 0, stream>>>(qx, kvx, qxb, kvxb,
                                                Wq, Wk, Wv, Wg, Wo,
                                                WqT, WkT, WvT, WgT, WoT);
    proj_mfma<<<dim3(4, 64, 4), 256, 0, stream>>>(qxb, kvxb, WqT, WkT, WvT, WgT,
                                                  bg, Qw, Kw, Vt, Gw);
    attn_kernel<<<dim3(512), 256, 0, stream>>>(Qw, Kw, Vt, bias, Gw, Owg);
    out_mfma<<<dim3(4, 64, 1), 256, 0, stream>>>(Owg, WoT, bo, out);
}